// Round 16
// baseline (313.537 us; speedup 1.0000x reference)
//
#include <hip/hip_runtime.h>

typedef unsigned int uint;
typedef unsigned short ushort;
typedef __attribute__((ext_vector_type(8))) short bf16x8;
typedef __attribute__((ext_vector_type(4))) float f32x4;

#define NN 4761            // 69*69
#define SZ_S 9043968       // 1024*69*128
#define NEGV -9000000.0f

// Native single-instruction transcendentals (base-2). v_log_f32(0) = -inf,
// v_exp_f32(-inf) = 0 -> masked elements produce p = 0 exactly.
__device__ __forceinline__ float fexp2(float x) {
  float r; asm("v_exp_f32 %0, %1" : "=v"(r) : "v"(x)); return r;
}
__device__ __forceinline__ float flog2(float x) {
  float r; asm("v_log_f32 %0, %1" : "=v"(r) : "v"(x)); return r;
}
// Packed f32->2xbf16 (RNE). Pack-order convention cancels between A and B operands.
__device__ __forceinline__ uint cvtpk(float lo, float hi) {
  uint r; asm("v_cvt_pk_bf16_f32 %0, %1, %2" : "=v"(r) : "v"(lo), "v"(hi)); return r;
}
__device__ __forceinline__ float b2f_lo(uint u) { return __uint_as_float(u << 16); }
__device__ __forceinline__ float b2f_hi(uint u) { return __uint_as_float(u & 0xFFFF0000u); }
__device__ __forceinline__ ushort f2b(float f) {
  uint x = __float_as_uint(f);
  x += 0x7FFFu + ((x >> 16) & 1u);
  return (ushort)(x >> 16);
}

// 16-lane group reductions via xor-butterfly shuffles (bitwise lane-uniform; see r10
// post-mortem -- DPP row_ror reductions are NOT lane-uniform, caused replay failure).
__device__ __forceinline__ float gsum16(float s) {
  #pragma unroll
  for (int d = 1; d < 16; d <<= 1) s += __shfl_xor(s, d, 16);
  return s;
}
__device__ __forceinline__ float gmax16(float m) {
  #pragma unroll
  for (int d = 1; d < 16; d <<= 1) m = fmaxf(m, __shfl_xor(m, d, 16));
  return m;
}

// ---------------- K0: batch-independent projections for alpha_str.
// v[d] = sum_i wS[i]*W[i][d]  (W^T @ wS); bwS = sum_i bl[i]*wS[i].
// Stored in the alpha buffer: v at [3072..3199], bwS at [3200].
__global__ __launch_bounds__(128) void k0_wproj(
    const float* __restrict__ Wl, const float* __restrict__ bl,
    const float* __restrict__ wSp, float* __restrict__ alpha) {
  __shared__ float red[2];
  const int d = threadIdx.x;
  float v = 0.0f;
  #pragma unroll 8
  for (int i = 0; i < 128; ++i) v = fmaf(wSp[i], Wl[i * 128 + d], v);
  alpha[3072 + d] = v;
  float t = bl[d] * wSp[d];
  for (int off = 32; off >= 1; off >>= 1) t += __shfl_down(t, off);
  if ((d & 63) == 0) red[d >> 6] = t;
  __syncthreads();
  if (d == 0) alpha[3200] = red[0] + red[1];
}

// ---------------- K1 (MFMA): Sb = bf16(se @ W^T + b). 3-term precision split keeps S at
// one-bf16-rounding accuracy: S ~= seh@Wh + sel@Wh + seh@Wr (sel@Wr ~1e-5 rel, dropped).
__global__ __launch_bounds__(512) void k1_mfma(
    const float* __restrict__ se, const float* __restrict__ Wl,
    const float* __restrict__ bl, ushort* __restrict__ Sb) {
  __shared__ ushort Hh[80 * 128];   // 20,480 B  bf16(se), swizzled
  __shared__ ushort Hl[80 * 128];   // 20,480 B  bf16(se - bf16(se))
  __shared__ ushort Wh[128 * 128];  // 32,768 B  bf16(W), swizzled
  __shared__ ushort Wr[128 * 128];  // 32,768 B  bf16(W - bf16(W))
  __shared__ float bld[128];
  const int tid = threadIdx.x, b = blockIdx.x;
  for (int idx = tid; idx < 80 * 32; idx += 512) {
    int r = idx >> 5, q = idx & 31, d0 = q << 2;
    uint2 ph, pl;
    if (r < 69) {
      float4 v = *(const float4*)(se + (b * 69 + r) * 128 + d0);
      ph.x = cvtpk(v.x, v.y); ph.y = cvtpk(v.z, v.w);
      float rx = v.x - b2f_lo(ph.x), ry = v.y - b2f_hi(ph.x);
      float rz = v.z - b2f_lo(ph.y), rw = v.w - b2f_hi(ph.y);
      pl.x = cvtpk(rx, ry); pl.y = cvtpk(rz, rw);
    } else { ph.x = 0u; ph.y = 0u; pl.x = 0u; pl.y = 0u; }
    int off = r * 256 + (((d0 >> 3) ^ (r & 7)) << 4) + ((d0 & 7) << 1);
    *(uint2*)((char*)Hh + off) = ph;
    *(uint2*)((char*)Hl + off) = pl;
  }
  for (int idx = tid; idx < 128 * 32; idx += 512) {
    int r = idx >> 5, q = idx & 31, d0 = q << 2;
    float4 v = *(const float4*)(Wl + r * 128 + d0);
    uint2 ph, pl;
    ph.x = cvtpk(v.x, v.y); ph.y = cvtpk(v.z, v.w);
    float rx = v.x - b2f_lo(ph.x), ry = v.y - b2f_hi(ph.x);
    float rz = v.z - b2f_lo(ph.y), rw = v.w - b2f_hi(ph.y);
    pl.x = cvtpk(rx, ry); pl.y = cvtpk(rz, rw);
    int off = r * 256 + (((d0 >> 3) ^ (r & 7)) << 4) + ((d0 & 7) << 1);
    *(uint2*)((char*)Wh + off) = ph;
    *(uint2*)((char*)Wr + off) = pl;
  }
  if (tid < 128) bld[tid] = bl[tid];
  __syncthreads();
  const int wv = tid >> 6, l = tid & 63, lc = l & 15, lq = l >> 4;
  const int rb = wv * 16 + lc;            // W row (col-tile = wave id)
  const float bia = bld[rb];
  for (int rt = 0; rt < 5; ++rt) {
    const int ra = rt * 16 + lc;
    f32x4 acc = {0, 0, 0, 0};
    #pragma unroll
    for (int ks = 0; ks < 4; ++ks) {
      const int d0 = ks * 32 + lq * 8;
      uint4 ah = *(const uint4*)((const char*)Hh + ra * 256 + (((d0 >> 3) ^ (ra & 7)) << 4));
      uint4 al = *(const uint4*)((const char*)Hl + ra * 256 + (((d0 >> 3) ^ (ra & 7)) << 4));
      uint4 bh = *(const uint4*)((const char*)Wh + rb * 256 + (((d0 >> 3) ^ (rb & 7)) << 4));
      uint4 br = *(const uint4*)((const char*)Wr + rb * 256 + (((d0 >> 3) ^ (rb & 7)) << 4));
      acc = __builtin_amdgcn_mfma_f32_16x16x32_bf16(__builtin_bit_cast(bf16x8, ah),
                                                    __builtin_bit_cast(bf16x8, bh), acc, 0, 0, 0);
      acc = __builtin_amdgcn_mfma_f32_16x16x32_bf16(__builtin_bit_cast(bf16x8, al),
                                                    __builtin_bit_cast(bf16x8, bh), acc, 0, 0, 0);
      acc = __builtin_amdgcn_mfma_f32_16x16x32_bf16(__builtin_bit_cast(bf16x8, ah),
                                                    __builtin_bit_cast(bf16x8, br), acc, 0, 0, 0);
    }
    #pragma unroll
    for (int r_ = 0; r_ < 4; ++r_) {
      int ib = rt * 16 + lq * 4 + r_;
      if (ib < 69) Sb[(b * 69 + ib) * 128 + rb] = f2b(acc[r_] + bia);
    }
  }
}

// ---------------- K2: alphas (stores am1): [0..1023]=sem1, [1024..]=sem2, [2048..]=str.
__global__ __launch_bounds__(128) void k2_alpha(
    const float* __restrict__ in1, const float* __restrict__ in2,
    const float* __restrict__ se, const float* __restrict__ mask,
    const int* __restrict__ iidx,
    const float* __restrict__ w1p, const float* __restrict__ b1p,
    const float* __restrict__ w2p, const float* __restrict__ b2p,
    const float* __restrict__ bSp, float* __restrict__ alpha) {
  __shared__ float red[3][2];
  const int b = blockIdx.x, d = threadIdx.x;
  const int last = iidx[b * 69 + 68];
  float a1 = 0, a2 = 0, aS = 0, am = 0;
  const float* p1 = in1 + b * 69 * 128 + d;
  const float* p2 = in2 + b * 69 * 128 + d;
  const float* pS = se + b * 69 * 128 + d;
  const float* pm = mask + b * 69;
  for (int n = 0; n < 69; ++n) {
    float m = pm[n];
    a1 += p1[n * 128] * m;
    a2 += p2[n * 128] * m;
    aS += pS[n * 128] * m;
    am += m;
  }
  float z1 = (a1 / am + p1[last * 128]) * w1p[d];
  float z2 = (a2 / am + p2[last * 128]) * w2p[d];
  float zS = (aS / am + pS[last * 128]) * alpha[3072 + d];  // u_d * v_d
  for (int off = 32; off >= 1; off >>= 1) {
    z1 += __shfl_down(z1, off);
    z2 += __shfl_down(z2, off);
    zS += __shfl_down(zS, off);
  }
  if ((d & 63) == 0) { int wv = d >> 6; red[0][wv] = z1; red[1][wv] = z2; red[2][wv] = zS; }
  __syncthreads();
  if (d == 0) {
    float bwS = alpha[3200];
    float r1 = 1.0f / (1.0f + expf(-(red[0][0] + red[0][1] + b1p[0]))) + 1.0f;
    float r2 = 1.0f / (1.0f + expf(-(red[1][0] + red[1][1] + b2p[0]))) + 1.0f;
    float rS = 1.0f / (1.0f + expf(-(red[2][0] + red[2][1] + 2.0f * bwS + bSp[0]))) + 1.0f;
    if (r1 == 1.0f) r1 = 1.0001f;
    if (r2 == 1.0f) r2 = 1.0001f;
    if (rS == 1.0f) rS = 1.0001f;
    alpha[b] = r1 - 1.0f;
    alpha[1024 + b] = r2 - 1.0f;
    alpha[2048 + b] = rS - 1.0f;
  }
}

// ---------------- K3 (MFMA): E_k = (H o w_k) @ H^T; y=0 sources f32 hA, y=1 sources
// bf16 Sb. Symmetric -> 15 upper 16x16 tiles of padded 80x80. Row-grouped schedule
// (r15): consecutive tiles in a wave share the A row-tile -> 7 rescales instead of 15.
__global__ __launch_bounds__(256) void k3_scores(
    const float* __restrict__ hA, const float* __restrict__ W4A, float* __restrict__ dstA,
    const ushort* __restrict__ Sb, const float* __restrict__ W4B, float* __restrict__ dstB,
    const int* __restrict__ adj) {
  const int b = blockIdx.x, tid = threadIdx.x;
  const int srcS = blockIdx.y;
  const float* W4 = srcS ? W4B : W4A;
  float* dst      = srcS ? dstB : dstA;
  __shared__ ushort Hb[80 * 128];       // bf16, row pitch 256 B, XOR-swizzled chunks
  __shared__ uint W4b[4 * 64];          // bf16-packed W4
  __shared__ signed char adjld[69 * 70];
  for (int idx = tid; idx < 80 * 32; idx += 256) {
    int r = idx >> 5, q = idx & 31, d0 = q << 2;
    uint2 pk;
    if (r < 69) {
      if (srcS) {
        pk = *(const uint2*)(Sb + (b * 69 + r) * 128 + d0);
      } else {
        float4 v = *(const float4*)(hA + (b * 69 + r) * 128 + d0);
        pk.x = cvtpk(v.x, v.y);
        pk.y = cvtpk(v.z, v.w);
      }
    } else { pk.x = 0u; pk.y = 0u; }
    *(uint2*)((char*)Hb + r * 256 + (((d0 >> 3) ^ (r & 7)) << 4) + ((d0 & 7) << 1)) = pk;
  }
  {
    int k = tid >> 6, dp = (tid & 63) << 1;
    W4b[k * 64 + (tid & 63)] = cvtpk(W4[k * 128 + dp], W4[k * 128 + dp + 1]);
  }
  for (int idx = tid; idx < NN; idx += 256)
    adjld[(idx / 69) * 70 + (idx % 69)] = (signed char)adj[b * NN + idx];
  __syncthreads();
  const int wv = tid >> 6, l = tid & 63;
  const int lc = l & 15, lq = l >> 4;
  // Row-grouped schedule, byte t = (ti<<4)|tj, 0xFF = none:
  //  w0: (0,0)(0,1)(0,2)(0,3)   w1: (0,4)(1,1)(1,2)(1,3)
  //  w2: (1,4)(2,2)(2,3)(2,4)   w3: (3,3)(3,4)(4,4)
  const uint e = (wv == 0) ? 0x03020100u : (wv == 1) ? 0x13121104u
               : (wv == 2) ? 0x24232214u : 0xFF443433u;
  uint4 ak[4][4];  // [ks][k] cached A-frags for the current row-tile
  int prev_ti = -1;
  #pragma unroll
  for (int t = 0; t < 4; ++t) {
    const int byte = (int)((e >> (8 * t)) & 0xFFu);
    if (byte != 0xFF) {
      const int ti = byte >> 4, tj = byte & 15;
      const int ra = ti * 16 + lc, rb = tj * 16 + lc;
      if (ti != prev_ti) {  // wave-uniform branch
        prev_ti = ti;
        #pragma unroll
        for (int ks = 0; ks < 4; ++ks) {
          const int d0 = ks * 32 + lq * 8;
          uint4 araw = *(const uint4*)((const char*)Hb + ra * 256 + (((d0 >> 3) ^ (ra & 7)) << 4));
          float a0 = b2f_lo(araw.x), a1 = b2f_hi(araw.x);
          float a2 = b2f_lo(araw.y), a3 = b2f_hi(araw.y);
          float a4 = b2f_lo(araw.z), a5 = b2f_hi(araw.z);
          float a6 = b2f_lo(araw.w), a7 = b2f_hi(araw.w);
          #pragma unroll
          for (int k = 0; k < 4; ++k) {
            uint4 wq = *(const uint4*)(W4b + k * 64 + (d0 >> 1));
            ak[ks][k].x = cvtpk(a0 * b2f_lo(wq.x), a1 * b2f_hi(wq.x));
            ak[ks][k].y = cvtpk(a2 * b2f_lo(wq.y), a3 * b2f_hi(wq.y));
            ak[ks][k].z = cvtpk(a4 * b2f_lo(wq.z), a5 * b2f_hi(wq.z));
            ak[ks][k].w = cvtpk(a6 * b2f_lo(wq.w), a7 * b2f_hi(wq.w));
          }
        }
      }
      f32x4 acc0 = {0,0,0,0}, acc1 = {0,0,0,0}, acc2 = {0,0,0,0}, acc3 = {0,0,0,0};
      #pragma unroll
      for (int ks = 0; ks < 4; ++ks) {
        const int d0 = ks * 32 + lq * 8;
        uint4 braw = *(const uint4*)((const char*)Hb + rb * 256 + (((d0 >> 3) ^ (rb & 7)) << 4));
        bf16x8 bfrag = __builtin_bit_cast(bf16x8, braw);
        acc0 = __builtin_amdgcn_mfma_f32_16x16x32_bf16(__builtin_bit_cast(bf16x8, ak[ks][0]), bfrag, acc0, 0, 0, 0);
        acc1 = __builtin_amdgcn_mfma_f32_16x16x32_bf16(__builtin_bit_cast(bf16x8, ak[ks][1]), bfrag, acc1, 0, 0, 0);
        acc2 = __builtin_amdgcn_mfma_f32_16x16x32_bf16(__builtin_bit_cast(bf16x8, ak[ks][2]), bfrag, acc2, 0, 0, 0);
        acc3 = __builtin_amdgcn_mfma_f32_16x16x32_bf16(__builtin_bit_cast(bf16x8, ak[ks][3]), bfrag, acc3, 0, 0, 0);
      }
      const bool diag = (ti == tj);
      #pragma unroll
      for (int r = 0; r < 4; ++r) {
        const int ib = ti * 16 + lq * 4 + r;
        const int jb = tj * 16 + lc;
        if (ib < 69 && jb < 69 && (!diag || ib <= jb)) {
          const float e0 = acc0[r], e1 = acc1[r], e2 = acc2[r], e3 = acc3[r];
          const int aij = adjld[ib * 70 + jb];
          float sA = (aij <= 1) ? e0 : (aij == 2) ? e1 : (aij == 3) ? e2 : e3;
          sA = (sA >= 0.0f) ? sA : 0.2f * sA;
          if (aij < 1) sA = NEGV;
          dst[b * NN + ib * 69 + jb] = sA;
          const int aji = adjld[jb * 70 + ib];
          float sB = (aji <= 1) ? e0 : (aji == 2) ? e1 : (aji == 3) ? e2 : e3;
          sB = (sB >= 0.0f) ? sB : 0.2f * sB;
          if (aji < 1) sB = NEGV;
          dst[b * NN + jb * 69 + ib] = sB;
        }
      }
    }
  }
}

// ---------------- K4: entmax, 16-lanes-per-row (wave = 4 rows), native v_exp/v_log,
// xor-butterfly reductions (lane-uniform). r16: sides A and B bisected in ONE
// interleaved loop -- two independent dependency chains fill the butterfly/trans
// latency bubbles (VALUBusy was 82%). Per-side FP op sequences are bitwise identical
// to the sequential version; 15 iters; final p-sweep fused (last midpoint IS tau).
__device__ __forceinline__ float pcomp(float xs, float tau, float q) {
  float v = fmaxf(xs - tau, 0.0f);
  return fexp2(q * flog2(v));  // v=0 -> log=-inf -> exp2(-inf)=0
}

__global__ __launch_bounds__(256) void k4_entmax(
    const float* __restrict__ alpha, int o,
    float* __restrict__ scA, const float* __restrict__ scB) {
  const int tid = threadIdx.x;
  const int wave = tid >> 6, lane = tid & 63;
  const int grp = lane >> 4, l16 = lane & 15;
  const int row = blockIdx.x * 16 + wave * 4 + grp;  // 0..70655 (4416 blocks)
  const int b = row / 69;
  const float am1A = alpha[o * 1024 + b];
  const float am1B = alpha[2048 + b];
  float* rowA = scA + 69u * (uint)row;
  const float* rowB = scB + 69u * (uint)row;
  const float qA = 1.0f / am1A, qB = 1.0f / am1B;
  float xa[5], xb[5];
  #pragma unroll
  for (int s = 0; s < 5; ++s) {
    int j = s * 16 + l16;
    xa[s] = (j < 69) ? rowA[j] * am1A : -1.0e30f;  // pad -> v=0 -> p=0
    xb[s] = (j < 69) ? rowB[j] * am1B : -1.0e30f;
  }
  const float mxA = gmax16(fmaxf(fmaxf(fmaxf(xa[0], xa[1]), fmaxf(xa[2], xa[3])), xa[4]));
  const float mxB = gmax16(fmaxf(fmaxf(fmaxf(xb[0], xb[1]), fmaxf(xb[2], xb[3])), xb[4]));
  float loA = mxA - 1.0f;
  float dmA = (mxA - fexp2(am1A * flog2(1.0f / 69.0f))) - loA;
  float loB = mxB - 1.0f;
  float dmB = (mxB - fexp2(am1B * flog2(1.0f / 69.0f))) - loB;
  float pa0 = 0, pa1 = 0, pa2 = 0, pa3 = 0, pa4 = 0, sA = 0;
  float pb0 = 0, pb1 = 0, pb2 = 0, pb3 = 0, pb4 = 0, sB = 0;
  #pragma unroll 1
  for (int it = 0; it < 15; ++it) {
    dmA *= 0.5f; const float tmA = loA + dmA;
    dmB *= 0.5f; const float tmB = loB + dmB;
    pa0 = pcomp(xa[0], tmA, qA); pb0 = pcomp(xb[0], tmB, qB);
    pa1 = pcomp(xa[1], tmA, qA); pb1 = pcomp(xb[1], tmB, qB);
    pa2 = pcomp(xa[2], tmA, qA); pb2 = pcomp(xb[2], tmB, qB);
    pa3 = pcomp(xa[3], tmA, qA); pb3 = pcomp(xb[3], tmB, qB);
    pa4 = pcomp(xa[4], tmA, qA); pb4 = pcomp(xb[4], tmB, qB);
    sA = gsum16(pa0 + pa1 + pa2 + pa3 + pa4);
    sB = gsum16(pb0 + pb1 + pb2 + pb3 + pb4);
    if (sA >= 1.0f) loA = tmA;  // butterfly sums are bitwise lane-uniform
    if (sB >= 1.0f) loB = tmB;
  }
  const float rsA = 1.0f / sA, rsB = 1.0f / sB;
  // ---- combine: w = (pA/sA)*(pB/sB) / (sum + 1e-7)
  float w0 = (pa0 * rsA) * (pb0 * rsB);
  float w1 = (pa1 * rsA) * (pb1 * rsB);
  float w2 = (pa2 * rsA) * (pb2 * rsB);
  float w3 = (pa3 * rsA) * (pb3 * rsB);
  float w4 = (pa4 * rsA) * (pb4 * rsB);
  const float ws = gsum16(w0 + w1 + w2 + w3 + w4);
  const float rden = 1.0f / (ws + 1e-7f);
  if (l16 < 5) {}  // (keep structure simple; bounds below)
  {
    int j = 0 * 16 + l16; if (j < 69) rowA[j] = w0 * rden;
  }
  { int j = 1 * 16 + l16; if (j < 69) rowA[j] = w1 * rden; }
  { int j = 2 * 16 + l16; if (j < 69) rowA[j] = w2 * rden; }
  { int j = 3 * 16 + l16; if (j < 69) rowA[j] = w3 * rden; }
  { int j = 4 * 16 + l16; if (j < 69) rowA[j] = w4 * rden; }
}

// ---------------- K5: out = w @ h (w f32 row-major, h f32, out f32)
__global__ __launch_bounds__(256) void k5_out(
    const float* __restrict__ h, const float* __restrict__ wsrc,
    float* __restrict__ outp) {
  const int b = blockIdx.x, tid = threadIdx.x;
  __shared__ float hld[69 * 132];  // 36,432 B
  __shared__ float wld[69 * 70];   // 19,320 B
  for (int idx = tid; idx < 69 * 128; idx += 256) {
    int r = idx >> 7, d = idx & 127;
    hld[r * 132 + d] = h[(b * 69 + r) * 128 + d];
  }
  for (int idx = tid; idx < NN; idx += 256) {
    int i = idx / 69, j = idx - i * 69;
    wld[i * 70 + j] = wsrc[b * NN + idx];
  }
  __syncthreads();
  for (int s = tid; s < 69 * 32; s += 256) {
    int i = s >> 5, dq = s & 31, d0 = dq << 2;
    float acc0 = 0, acc1 = 0, acc2 = 0, acc3 = 0;
    const float* wrow = wld + i * 70;
    const float* hcol = hld + d0;
    for (int j = 0; j < 69; ++j) {
      float wv = wrow[j];
      float4 hv = *(const float4*)(hcol + j * 132);
      acc0 = fmaf(wv, hv.x, acc0);
      acc1 = fmaf(wv, hv.y, acc1);
      acc2 = fmaf(wv, hv.z, acc2);
      acc3 = fmaf(wv, hv.w, acc3);
    }
    float4 ov = make_float4(acc0, acc1, acc2, acc3);
    *(float4*)(outp + (b * 69 + i) * 128 + d0) = ov;
  }
}

extern "C" void kernel_launch(void* const* d_in, const int* in_sizes, int n_in,
                              void* d_out, int out_size, void* d_ws, size_t ws_size,
                              hipStream_t stream) {
  (void)in_sizes; (void)n_in; (void)out_size;
  // Sb(bf16) 18,087,936 | alpha 16,384 | scA 19,501,056 | scB 19,501,056 = 57,106,432 B
  if (ws_size < 57106432u) return;  // early-return signature: absmax == 7.08e-2
  const float* in1 = (const float*)d_in[0];
  const float* in2 = (const float*)d_in[1];
  const float* se  = (const float*)d_in[2];
  const int* adjS  = (const int*)d_in[3];
  const int* adjND = (const int*)d_in[4];
  const float* mask = (const float*)d_in[5];
  const int* iidx  = (const int*)d_in[6];
  const float* Wl  = (const float*)d_in[8];
  const float* bl  = (const float*)d_in[9];
  const float* w1p = (const float*)d_in[10];
  const float* b1p = (const float*)d_in[11];
  const float* w2p = (const float*)d_in[12];
  const float* b2p = (const float*)d_in[13];
  const float* wSp = (const float*)d_in[14];
  const float* bSp = (const float*)d_in[15];
  const float* A1  = (const float*)d_in[16];
  const float* S1  = (const float*)d_in[17];
  const float* A2  = (const float*)d_in[18];
  const float* S2  = (const float*)d_in[19];
  ushort* Sb   = (ushort*)d_ws;
  float* alpha = (float*)((char*)d_ws + 18087936);
  float* scA   = (float*)((char*)d_ws + 18104320);
  float* scB   = (float*)((char*)d_ws + 37605376);
  float* outp  = (float*)d_out;

  k0_wproj<<<dim3(1), dim3(128), 0, stream>>>(Wl, bl, wSp, alpha);
  k1_mfma<<<dim3(1024), dim3(512), 0, stream>>>(se, Wl, bl, Sb);
  k2_alpha<<<dim3(1024), dim3(128), 0, stream>>>(in1, in2, se, mask, iidx,
                                                 w1p, b1p, w2p, b2p, bSp, alpha);
  // out1
  k3_scores<<<dim3(1024, 2), dim3(256), 0, stream>>>(in1, A1, scA, Sb, S1, scB, adjS);
  k4_entmax<<<dim3(4416), dim3(256), 0, stream>>>(alpha, 0, scA, scB);
  k5_out<<<dim3(1024), dim3(256), 0, stream>>>(in1, scA, outp);
  // out2
  k3_scores<<<dim3(1024, 2), dim3(256), 0, stream>>>(in2, A2, scA, Sb, S2, scB, adjND);
  k4_entmax<<<dim3(4416), dim3(256), 0, stream>>>(alpha, 1, scA, scB);
  k5_out<<<dim3(1024), dim3(256), 0, stream>>>(in2, scA, outp + SZ_S);
}

// Round 17
// 299.022 us; speedup vs baseline: 1.0485x; 1.0485x over previous
//
#include <hip/hip_runtime.h>

typedef unsigned int uint;
typedef unsigned short ushort;
typedef __attribute__((ext_vector_type(8))) short bf16x8;
typedef __attribute__((ext_vector_type(4))) float f32x4;

#define NN 4761            // 69*69
#define SZ_S 9043968       // 1024*69*128
#define NEGV -9000000.0f

// Native single-instruction transcendentals (base-2). v_log_f32(0) = -inf,
// v_exp_f32(-inf) = 0 -> masked elements produce p = 0 exactly.
__device__ __forceinline__ float fexp2(float x) {
  float r; asm("v_exp_f32 %0, %1" : "=v"(r) : "v"(x)); return r;
}
__device__ __forceinline__ float flog2(float x) {
  float r; asm("v_log_f32 %0, %1" : "=v"(r) : "v"(x)); return r;
}
// Packed f32->2xbf16 (RNE). Pack-order convention cancels between A and B operands.
__device__ __forceinline__ uint cvtpk(float lo, float hi) {
  uint r; asm("v_cvt_pk_bf16_f32 %0, %1, %2" : "=v"(r) : "v"(lo), "v"(hi)); return r;
}
__device__ __forceinline__ float b2f_lo(uint u) { return __uint_as_float(u << 16); }
__device__ __forceinline__ float b2f_hi(uint u) { return __uint_as_float(u & 0xFFFF0000u); }
__device__ __forceinline__ ushort f2b(float f) {
  uint x = __float_as_uint(f);
  x += 0x7FFFu + ((x >> 16) & 1u);
  return (ushort)(x >> 16);
}

// 16-lane group reductions via xor-butterfly shuffles (bitwise lane-uniform; see r10
// post-mortem -- DPP row_ror reductions are NOT lane-uniform, caused replay failure).
// r16 post-mortem: k4 is trans-pipe-bound; A/B ILP interleave was neutral-negative.
__device__ __forceinline__ float gsum16(float s) {
  #pragma unroll
  for (int d = 1; d < 16; d <<= 1) s += __shfl_xor(s, d, 16);
  return s;
}
__device__ __forceinline__ float gmax16(float m) {
  #pragma unroll
  for (int d = 1; d < 16; d <<= 1) m = fmaxf(m, __shfl_xor(m, d, 16));
  return m;
}

// ---------------- K0: batch-independent projections for alpha_str.
// v[d] = sum_i wS[i]*W[i][d]  (W^T @ wS); bwS = sum_i bl[i]*wS[i].
// Stored in the alpha buffer: v at [3072..3199], bwS at [3200].
__global__ __launch_bounds__(128) void k0_wproj(
    const float* __restrict__ Wl, const float* __restrict__ bl,
    const float* __restrict__ wSp, float* __restrict__ alpha) {
  __shared__ float red[2];
  const int d = threadIdx.x;
  float v = 0.0f;
  #pragma unroll 8
  for (int i = 0; i < 128; ++i) v = fmaf(wSp[i], Wl[i * 128 + d], v);
  alpha[3072 + d] = v;
  float t = bl[d] * wSp[d];
  for (int off = 32; off >= 1; off >>= 1) t += __shfl_down(t, off);
  if ((d & 63) == 0) red[d >> 6] = t;
  __syncthreads();
  if (d == 0) alpha[3200] = red[0] + red[1];
}

// ---------------- K1 (MFMA): Sb = bf16(se @ W^T + b). 3-term precision split keeps S at
// one-bf16-rounding accuracy: S ~= seh@Wh + sel@Wh + seh@Wr (sel@Wr ~1e-5 rel, dropped).
__global__ __launch_bounds__(512) void k1_mfma(
    const float* __restrict__ se, const float* __restrict__ Wl,
    const float* __restrict__ bl, ushort* __restrict__ Sb) {
  __shared__ ushort Hh[80 * 128];   // 20,480 B  bf16(se), swizzled
  __shared__ ushort Hl[80 * 128];   // 20,480 B  bf16(se - bf16(se))
  __shared__ ushort Wh[128 * 128];  // 32,768 B  bf16(W), swizzled
  __shared__ ushort Wr[128 * 128];  // 32,768 B  bf16(W - bf16(W))
  __shared__ float bld[128];
  const int tid = threadIdx.x, b = blockIdx.x;
  for (int idx = tid; idx < 80 * 32; idx += 512) {
    int r = idx >> 5, q = idx & 31, d0 = q << 2;
    uint2 ph, pl;
    if (r < 69) {
      float4 v = *(const float4*)(se + (b * 69 + r) * 128 + d0);
      ph.x = cvtpk(v.x, v.y); ph.y = cvtpk(v.z, v.w);
      float rx = v.x - b2f_lo(ph.x), ry = v.y - b2f_hi(ph.x);
      float rz = v.z - b2f_lo(ph.y), rw = v.w - b2f_hi(ph.y);
      pl.x = cvtpk(rx, ry); pl.y = cvtpk(rz, rw);
    } else { ph.x = 0u; ph.y = 0u; pl.x = 0u; pl.y = 0u; }
    int off = r * 256 + (((d0 >> 3) ^ (r & 7)) << 4) + ((d0 & 7) << 1);
    *(uint2*)((char*)Hh + off) = ph;
    *(uint2*)((char*)Hl + off) = pl;
  }
  for (int idx = tid; idx < 128 * 32; idx += 512) {
    int r = idx >> 5, q = idx & 31, d0 = q << 2;
    float4 v = *(const float4*)(Wl + r * 128 + d0);
    uint2 ph, pl;
    ph.x = cvtpk(v.x, v.y); ph.y = cvtpk(v.z, v.w);
    float rx = v.x - b2f_lo(ph.x), ry = v.y - b2f_hi(ph.x);
    float rz = v.z - b2f_lo(ph.y), rw = v.w - b2f_hi(ph.y);
    pl.x = cvtpk(rx, ry); pl.y = cvtpk(rz, rw);
    int off = r * 256 + (((d0 >> 3) ^ (r & 7)) << 4) + ((d0 & 7) << 1);
    *(uint2*)((char*)Wh + off) = ph;
    *(uint2*)((char*)Wr + off) = pl;
  }
  if (tid < 128) bld[tid] = bl[tid];
  __syncthreads();
  const int wv = tid >> 6, l = tid & 63, lc = l & 15, lq = l >> 4;
  const int rb = wv * 16 + lc;            // W row (col-tile = wave id)
  const float bia = bld[rb];
  for (int rt = 0; rt < 5; ++rt) {
    const int ra = rt * 16 + lc;
    f32x4 acc = {0, 0, 0, 0};
    #pragma unroll
    for (int ks = 0; ks < 4; ++ks) {
      const int d0 = ks * 32 + lq * 8;
      uint4 ah = *(const uint4*)((const char*)Hh + ra * 256 + (((d0 >> 3) ^ (ra & 7)) << 4));
      uint4 al = *(const uint4*)((const char*)Hl + ra * 256 + (((d0 >> 3) ^ (ra & 7)) << 4));
      uint4 bh = *(const uint4*)((const char*)Wh + rb * 256 + (((d0 >> 3) ^ (rb & 7)) << 4));
      uint4 br = *(const uint4*)((const char*)Wr + rb * 256 + (((d0 >> 3) ^ (rb & 7)) << 4));
      acc = __builtin_amdgcn_mfma_f32_16x16x32_bf16(__builtin_bit_cast(bf16x8, ah),
                                                    __builtin_bit_cast(bf16x8, bh), acc, 0, 0, 0);
      acc = __builtin_amdgcn_mfma_f32_16x16x32_bf16(__builtin_bit_cast(bf16x8, al),
                                                    __builtin_bit_cast(bf16x8, bh), acc, 0, 0, 0);
      acc = __builtin_amdgcn_mfma_f32_16x16x32_bf16(__builtin_bit_cast(bf16x8, ah),
                                                    __builtin_bit_cast(bf16x8, br), acc, 0, 0, 0);
    }
    #pragma unroll
    for (int r_ = 0; r_ < 4; ++r_) {
      int ib = rt * 16 + lq * 4 + r_;
      if (ib < 69) Sb[(b * 69 + ib) * 128 + rb] = f2b(acc[r_] + bia);
    }
  }
}

// ---------------- K2: alphas (stores am1): [0..1023]=sem1, [1024..]=sem2, [2048..]=str.
__global__ __launch_bounds__(128) void k2_alpha(
    const float* __restrict__ in1, const float* __restrict__ in2,
    const float* __restrict__ se, const float* __restrict__ mask,
    const int* __restrict__ iidx,
    const float* __restrict__ w1p, const float* __restrict__ b1p,
    const float* __restrict__ w2p, const float* __restrict__ b2p,
    const float* __restrict__ bSp, float* __restrict__ alpha) {
  __shared__ float red[3][2];
  const int b = blockIdx.x, d = threadIdx.x;
  const int last = iidx[b * 69 + 68];
  float a1 = 0, a2 = 0, aS = 0, am = 0;
  const float* p1 = in1 + b * 69 * 128 + d;
  const float* p2 = in2 + b * 69 * 128 + d;
  const float* pS = se + b * 69 * 128 + d;
  const float* pm = mask + b * 69;
  for (int n = 0; n < 69; ++n) {
    float m = pm[n];
    a1 += p1[n * 128] * m;
    a2 += p2[n * 128] * m;
    aS += pS[n * 128] * m;
    am += m;
  }
  float z1 = (a1 / am + p1[last * 128]) * w1p[d];
  float z2 = (a2 / am + p2[last * 128]) * w2p[d];
  float zS = (aS / am + pS[last * 128]) * alpha[3072 + d];  // u_d * v_d
  for (int off = 32; off >= 1; off >>= 1) {
    z1 += __shfl_down(z1, off);
    z2 += __shfl_down(z2, off);
    zS += __shfl_down(zS, off);
  }
  if ((d & 63) == 0) { int wv = d >> 6; red[0][wv] = z1; red[1][wv] = z2; red[2][wv] = zS; }
  __syncthreads();
  if (d == 0) {
    float bwS = alpha[3200];
    float r1 = 1.0f / (1.0f + expf(-(red[0][0] + red[0][1] + b1p[0]))) + 1.0f;
    float r2 = 1.0f / (1.0f + expf(-(red[1][0] + red[1][1] + b2p[0]))) + 1.0f;
    float rS = 1.0f / (1.0f + expf(-(red[2][0] + red[2][1] + 2.0f * bwS + bSp[0]))) + 1.0f;
    if (r1 == 1.0f) r1 = 1.0001f;
    if (r2 == 1.0f) r2 = 1.0001f;
    if (rS == 1.0f) rS = 1.0001f;
    alpha[b] = r1 - 1.0f;
    alpha[1024 + b] = r2 - 1.0f;
    alpha[2048 + b] = rS - 1.0f;
  }
}

// ---------------- K3 (MFMA): E_k = (H o w_k) @ H^T; y=0 sources f32 hA, y=1 sources
// bf16 Sb. Symmetric -> 15 upper 16x16 tiles of padded 80x80. Row-grouped schedule
// (r15): consecutive tiles in a wave share the A row-tile -> 7 rescales instead of 15.
__global__ __launch_bounds__(256) void k3_scores(
    const float* __restrict__ hA, const float* __restrict__ W4A, float* __restrict__ dstA,
    const ushort* __restrict__ Sb, const float* __restrict__ W4B, float* __restrict__ dstB,
    const int* __restrict__ adj) {
  const int b = blockIdx.x, tid = threadIdx.x;
  const int srcS = blockIdx.y;
  const float* W4 = srcS ? W4B : W4A;
  float* dst      = srcS ? dstB : dstA;
  __shared__ ushort Hb[80 * 128];       // bf16, row pitch 256 B, XOR-swizzled chunks
  __shared__ uint W4b[4 * 64];          // bf16-packed W4
  __shared__ signed char adjld[69 * 70];
  for (int idx = tid; idx < 80 * 32; idx += 256) {
    int r = idx >> 5, q = idx & 31, d0 = q << 2;
    uint2 pk;
    if (r < 69) {
      if (srcS) {
        pk = *(const uint2*)(Sb + (b * 69 + r) * 128 + d0);
      } else {
        float4 v = *(const float4*)(hA + (b * 69 + r) * 128 + d0);
        pk.x = cvtpk(v.x, v.y);
        pk.y = cvtpk(v.z, v.w);
      }
    } else { pk.x = 0u; pk.y = 0u; }
    *(uint2*)((char*)Hb + r * 256 + (((d0 >> 3) ^ (r & 7)) << 4) + ((d0 & 7) << 1)) = pk;
  }
  {
    int k = tid >> 6, dp = (tid & 63) << 1;
    W4b[k * 64 + (tid & 63)] = cvtpk(W4[k * 128 + dp], W4[k * 128 + dp + 1]);
  }
  for (int idx = tid; idx < NN; idx += 256)
    adjld[(idx / 69) * 70 + (idx % 69)] = (signed char)adj[b * NN + idx];
  __syncthreads();
  const int wv = tid >> 6, l = tid & 63;
  const int lc = l & 15, lq = l >> 4;
  // Row-grouped schedule, byte t = (ti<<4)|tj, 0xFF = none:
  //  w0: (0,0)(0,1)(0,2)(0,3)   w1: (0,4)(1,1)(1,2)(1,3)
  //  w2: (1,4)(2,2)(2,3)(2,4)   w3: (3,3)(3,4)(4,4)
  const uint e = (wv == 0) ? 0x03020100u : (wv == 1) ? 0x13121104u
               : (wv == 2) ? 0x24232214u : 0xFF443433u;
  uint4 ak[4][4];  // [ks][k] cached A-frags for the current row-tile
  int prev_ti = -1;
  #pragma unroll
  for (int t = 0; t < 4; ++t) {
    const int byte = (int)((e >> (8 * t)) & 0xFFu);
    if (byte != 0xFF) {
      const int ti = byte >> 4, tj = byte & 15;
      const int ra = ti * 16 + lc, rb = tj * 16 + lc;
      if (ti != prev_ti) {  // wave-uniform branch
        prev_ti = ti;
        #pragma unroll
        for (int ks = 0; ks < 4; ++ks) {
          const int d0 = ks * 32 + lq * 8;
          uint4 araw = *(const uint4*)((const char*)Hb + ra * 256 + (((d0 >> 3) ^ (ra & 7)) << 4));
          float a0 = b2f_lo(araw.x), a1 = b2f_hi(araw.x);
          float a2 = b2f_lo(araw.y), a3 = b2f_hi(araw.y);
          float a4 = b2f_lo(araw.z), a5 = b2f_hi(araw.z);
          float a6 = b2f_lo(araw.w), a7 = b2f_hi(araw.w);
          #pragma unroll
          for (int k = 0; k < 4; ++k) {
            uint4 wq = *(const uint4*)(W4b + k * 64 + (d0 >> 1));
            ak[ks][k].x = cvtpk(a0 * b2f_lo(wq.x), a1 * b2f_hi(wq.x));
            ak[ks][k].y = cvtpk(a2 * b2f_lo(wq.y), a3 * b2f_hi(wq.y));
            ak[ks][k].z = cvtpk(a4 * b2f_lo(wq.z), a5 * b2f_hi(wq.z));
            ak[ks][k].w = cvtpk(a6 * b2f_lo(wq.w), a7 * b2f_hi(wq.w));
          }
        }
      }
      f32x4 acc0 = {0,0,0,0}, acc1 = {0,0,0,0}, acc2 = {0,0,0,0}, acc3 = {0,0,0,0};
      #pragma unroll
      for (int ks = 0; ks < 4; ++ks) {
        const int d0 = ks * 32 + lq * 8;
        uint4 braw = *(const uint4*)((const char*)Hb + rb * 256 + (((d0 >> 3) ^ (rb & 7)) << 4));
        bf16x8 bfrag = __builtin_bit_cast(bf16x8, braw);
        acc0 = __builtin_amdgcn_mfma_f32_16x16x32_bf16(__builtin_bit_cast(bf16x8, ak[ks][0]), bfrag, acc0, 0, 0, 0);
        acc1 = __builtin_amdgcn_mfma_f32_16x16x32_bf16(__builtin_bit_cast(bf16x8, ak[ks][1]), bfrag, acc1, 0, 0, 0);
        acc2 = __builtin_amdgcn_mfma_f32_16x16x32_bf16(__builtin_bit_cast(bf16x8, ak[ks][2]), bfrag, acc2, 0, 0, 0);
        acc3 = __builtin_amdgcn_mfma_f32_16x16x32_bf16(__builtin_bit_cast(bf16x8, ak[ks][3]), bfrag, acc3, 0, 0, 0);
      }
      const bool diag = (ti == tj);
      #pragma unroll
      for (int r = 0; r < 4; ++r) {
        const int ib = ti * 16 + lq * 4 + r;
        const int jb = tj * 16 + lc;
        if (ib < 69 && jb < 69 && (!diag || ib <= jb)) {
          const float e0 = acc0[r], e1 = acc1[r], e2 = acc2[r], e3 = acc3[r];
          const int aij = adjld[ib * 70 + jb];
          float sA = (aij <= 1) ? e0 : (aij == 2) ? e1 : (aij == 3) ? e2 : e3;
          sA = (sA >= 0.0f) ? sA : 0.2f * sA;
          if (aij < 1) sA = NEGV;
          dst[b * NN + ib * 69 + jb] = sA;
          const int aji = adjld[jb * 70 + ib];
          float sB = (aji <= 1) ? e0 : (aji == 2) ? e1 : (aji == 3) ? e2 : e3;
          sB = (sB >= 0.0f) ? sB : 0.2f * sB;
          if (aji < 1) sB = NEGV;
          dst[b * NN + jb * 69 + ib] = sB;
        }
      }
    }
  }
}

// ---------------- K4: entmax, 16-lanes-per-row (wave = 4 rows), native v_exp/v_log,
// xor-butterfly reductions (lane-uniform), SEQUENTIAL sides (r16: interleave is
// neutral-negative; trans-pipe-bound). 13 iters: |tau err| <= dm0*2^-13 ~ 1.2e-4;
// normalization cancels common-mode dp/dtau to first order, residual w-err ~2e-4,
// ~7x under remaining tolerance headroom. Final p-sweep fused into the loop.
__device__ __forceinline__ float pcomp(float xs, float tau, float q) {
  float v = fmaxf(xs - tau, 0.0f);
  return fexp2(q * flog2(v));  // v=0 -> log=-inf -> exp2(-inf)=0
}

// In: x = scaled scores. Out: x = p values at the final tau; returns group-sum of p.
__device__ __forceinline__ float bisect13w(float (&x)[5], float am1, float q) {
  float mx = gmax16(fmaxf(fmaxf(fmaxf(x[0], x[1]), fmaxf(x[2], x[3])), x[4]));
  float tau_lo = mx - 1.0f;
  float tau_hi = mx - fexp2(am1 * flog2(1.0f / 69.0f));  // (1/d)^am1
  float dm = tau_hi - tau_lo;
  float p0 = 0, p1 = 0, p2 = 0, p3 = 0, p4 = 0, s = 0;
  #pragma unroll 1
  for (int it = 0; it < 13; ++it) {
    dm *= 0.5f;
    const float tm = tau_lo + dm;
    p0 = pcomp(x[0], tm, q);
    p1 = pcomp(x[1], tm, q);
    p2 = pcomp(x[2], tm, q);
    p3 = pcomp(x[3], tm, q);
    p4 = pcomp(x[4], tm, q);
    s = gsum16(p0 + p1 + p2 + p3 + p4);
    if (s >= 1.0f) tau_lo = tm;  // butterfly sum is bitwise lane-uniform
  }
  x[0] = p0; x[1] = p1; x[2] = p2; x[3] = p3; x[4] = p4;
  return s;
}

__global__ __launch_bounds__(256) void k4_entmax(
    const float* __restrict__ alpha, int o,
    float* __restrict__ scA, const float* __restrict__ scB) {
  const int tid = threadIdx.x;
  const int wave = tid >> 6, lane = tid & 63;
  const int grp = lane >> 4, l16 = lane & 15;
  const int row = blockIdx.x * 16 + wave * 4 + grp;  // 0..70655 (4416 blocks)
  const int b = row / 69;
  const float am1A = alpha[o * 1024 + b];
  const float am1B = alpha[2048 + b];
  float* rowA = scA + 69u * (uint)row;
  const float* rowB = scB + 69u * (uint)row;
  // ---- side A: bisect; x becomes p_A
  const float qA = 1.0f / am1A;
  float x[5], pa[5];
  #pragma unroll
  for (int s = 0; s < 5; ++s) {
    int j = s * 16 + l16;
    x[s] = (j < 69) ? rowA[j] * am1A : -1.0e30f;  // pad -> v=0 -> p=0
  }
  const float sA = bisect13w(x, am1A, qA);
  const float rsA = 1.0f / sA;
  #pragma unroll
  for (int s = 0; s < 5; ++s) pa[s] = x[s];
  // ---- side B (reuse x registers): x becomes p_B
  const float qB = 1.0f / am1B;
  #pragma unroll
  for (int s = 0; s < 5; ++s) {
    int j = s * 16 + l16;
    x[s] = (j < 69) ? rowB[j] * am1B : -1.0e30f;
  }
  const float sB = bisect13w(x, am1B, qB);
  const float rsB = 1.0f / sB;
  // ---- combine: w = (pA/sA)*(pB/sB) / (sum + 1e-7)
  float ws = 0.0f;
  #pragma unroll
  for (int s = 0; s < 5; ++s) { x[s] = (pa[s] * rsA) * (x[s] * rsB); ws += x[s]; }
  ws = gsum16(ws);
  const float rden = 1.0f / (ws + 1e-7f);
  #pragma unroll
  for (int s = 0; s < 5; ++s) {
    int j = s * 16 + l16;
    if (j < 69) rowA[j] = x[s] * rden;
  }
}

// ---------------- K5: out = w @ h (w f32 row-major, h f32, out f32)
__global__ __launch_bounds__(256) void k5_out(
    const float* __restrict__ h, const float* __restrict__ wsrc,
    float* __restrict__ outp) {
  const int b = blockIdx.x, tid = threadIdx.x;
  __shared__ float hld[69 * 132];  // 36,432 B
  __shared__ float wld[69 * 70];   // 19,320 B
  for (int idx = tid; idx < 69 * 128; idx += 256) {
    int r = idx >> 7, d = idx & 127;
    hld[r * 132 + d] = h[(b * 69 + r) * 128 + d];
  }
  for (int idx = tid; idx < NN; idx += 256) {
    int i = idx / 69, j = idx - i * 69;
    wld[i * 70 + j] = wsrc[b * NN + idx];
  }
  __syncthreads();
  for (int s = tid; s < 69 * 32; s += 256) {
    int i = s >> 5, dq = s & 31, d0 = dq << 2;
    float acc0 = 0, acc1 = 0, acc2 = 0, acc3 = 0;
    const float* wrow = wld + i * 70;
    const float* hcol = hld + d0;
    for (int j = 0; j < 69; ++j) {
      float wv = wrow[j];
      float4 hv = *(const float4*)(hcol + j * 132);
      acc0 = fmaf(wv, hv.x, acc0);
      acc1 = fmaf(wv, hv.y, acc1);
      acc2 = fmaf(wv, hv.z, acc2);
      acc3 = fmaf(wv, hv.w, acc3);
    }
    float4 ov = make_float4(acc0, acc1, acc2, acc3);
    *(float4*)(outp + (b * 69 + i) * 128 + d0) = ov;
  }
}

extern "C" void kernel_launch(void* const* d_in, const int* in_sizes, int n_in,
                              void* d_out, int out_size, void* d_ws, size_t ws_size,
                              hipStream_t stream) {
  (void)in_sizes; (void)n_in; (void)out_size;
  // Sb(bf16) 18,087,936 | alpha 16,384 | scA 19,501,056 | scB 19,501,056 = 57,106,432 B
  if (ws_size < 57106432u) return;  // early-return signature: absmax == 7.08e-2
  const float* in1 = (const float*)d_in[0];
  const float* in2 = (const float*)d_in[1];
  const float* se  = (const float*)d_in[2];
  const int* adjS  = (const int*)d_in[3];
  const int* adjND = (const int*)d_in[4];
  const float* mask = (const float*)d_in[5];
  const int* iidx  = (const int*)d_in[6];
  const float* Wl  = (const float*)d_in[8];
  const float* bl  = (const float*)d_in[9];
  const float* w1p = (const float*)d_in[10];
  const float* b1p = (const float*)d_in[11];
  const float* w2p = (const float*)d_in[12];
  const float* b2p = (const float*)d_in[13];
  const float* wSp = (const float*)d_in[14];
  const float* bSp = (const float*)d_in[15];
  const float* A1  = (const float*)d_in[16];
  const float* S1  = (const float*)d_in[17];
  const float* A2  = (const float*)d_in[18];
  const float* S2  = (const float*)d_in[19];
  ushort* Sb   = (ushort*)d_ws;
  float* alpha = (float*)((char*)d_ws + 18087936);
  float* scA   = (float*)((char*)d_ws + 18104320);
  float* scB   = (float*)((char*)d_ws + 37605376);
  float* outp  = (float*)d_out;

  k0_wproj<<<dim3(1), dim3(128), 0, stream>>>(Wl, bl, wSp, alpha);
  k1_mfma<<<dim3(1024), dim3(512), 0, stream>>>(se, Wl, bl, Sb);
  k2_alpha<<<dim3(1024), dim3(128), 0, stream>>>(in1, in2, se, mask, iidx,
                                                 w1p, b1p, w2p, b2p, bSp, alpha);
  // out1
  k3_scores<<<dim3(1024, 2), dim3(256), 0, stream>>>(in1, A1, scA, Sb, S1, scB, adjS);
  k4_entmax<<<dim3(4416), dim3(256), 0, stream>>>(alpha, 0, scA, scB);
  k5_out<<<dim3(1024), dim3(256), 0, stream>>>(in1, scA, outp);
  // out2
  k3_scores<<<dim3(1024, 2), dim3(256), 0, stream>>>(in2, A2, scA, Sb, S2, scB, adjND);
  k4_entmax<<<dim3(4416), dim3(256), 0, stream>>>(alpha, 1, scA, scB);
  k5_out<<<dim3(1024), dim3(256), 0, stream>>>(in2, scA, outp + SZ_S);
}